// Round 4
// baseline (776.698 us; speedup 1.0000x reference)
//
#include <hip/hip_runtime.h>
#include <hip/hip_fp16.h>
#include <hip/hip_cooperative_groups.h>

namespace cg = cooperative_groups;

#define NDIM 128     // OUT_DIM
#define KDIM 256     // IN_DIM
#define MT 5         // M-tiles (of 16 rows) per GEMM block
#define AROW 264     // LDS A-row stride in halfs (16B-aligned, breaks pow2)

// ---- fallback (round-3) CSR constants
#define CHUNK 3200   // edges per phase1/phase3 block (500 blocks)
#define BSH 9        // bucket = 512 nodes
#define BMASK 511
#define MAXBUCK 256  // >= NBUCK = ceil(N/512) = 196

// ---- cooperative CSR constants
#define CNBLK 1024   // cooperative grid (4 blocks/CU — co-resident)
#define CBSH 8       // bucket = 256 nodes
#define CBMASK 255

typedef _Float16 half8 __attribute__((ext_vector_type(8)));
typedef _Float16 half4v __attribute__((ext_vector_type(4)));
typedef float float4v __attribute__((ext_vector_type(4)));

// ---------- Wc = Wg @ Wp, written directly in MFMA B-fragment layout (fp16)
__global__ void k_combine_w(const float* __restrict__ Wp, const float* __restrict__ Wg,
                            _Float16* __restrict__ Bfrag) {
    int o = blockIdx.x;      // n: 0..127
    int i = threadIdx.x;     // k: 0..255
    float acc = 0.f;
#pragma unroll 4
    for (int k = 0; k < 128; ++k) acc = fmaf(Wg[o * 128 + k], Wp[k * 256 + i], acc);
    int kk = i >> 5, r = i & 31, quad = r >> 3, j = r & 7;
    int ntile = o >> 4, lanen = o & 15, lane = quad * 16 + lanen;
    Bfrag[(((ntile * 8 + kk) * 64) + lane) * 8 + j] = (_Float16)acc;
}

// ================= cooperative single-kernel CSR build =================
// Phases: A hist -> B1 local scan -> B2 top scan -> C scatter -> D fine sort.
// 4 grid.sync()s replace 5 kernel boundaries.
__global__ __launch_bounds__(256) void k_csr(const int* __restrict__ ei, int E, int N,
                                             int* __restrict__ tmp,
                                             int* __restrict__ sortedRow,
                                             int* __restrict__ cnt,
                                             int* __restrict__ rowStart,
                                             int* __restrict__ hist,
                                             int* __restrict__ blockSum) {
    cg::grid_group grid = cg::this_grid();
    __shared__ int sh[512];
    __shared__ int sh2[512];
    const int tid = threadIdx.x;
    const int blk = blockIdx.x;
    const int NBUCK = (N + CBMASK) >> CBSH;          // 391
    const int NE = NBUCK * CNBLK;                    // 400384
    const int SCCH = (NE + CNBLK - 1) / CNBLK;       // 391
    const int ECH = (E + CNBLK - 1) / CNBLK;         // 1563
    const int e0 = blk * ECH;
    const int e1 = min(e0 + ECH, E);
    const int* __restrict__ col = ei + E;

    // ---- A: per-block coarse histogram (bucket = tgt>>8)
    sh[tid] = 0; sh[tid + 256] = 0;
    __syncthreads();
    for (int e = e0 + tid; e < e1; e += 256) atomicAdd(&sh[col[e] >> CBSH], 1);
    __syncthreads();
    for (int b = tid; b < NBUCK; b += 256) hist[b * CNBLK + blk] = sh[b];

    grid.sync();   // (1)

    // ---- B1: per-block local exclusive scan of hist chunk [blk*SCCH, +SCCH)
    {
        int base = blk * SCCH;
        int lim = min(SCCH, NE - base);
        int i0 = base + tid * 2;
        int v0 = (tid * 2     < lim) ? hist[i0]     : 0;
        int v1 = (tid * 2 + 1 < lim) ? hist[i0 + 1] : 0;
        int mysum = v0 + v1;
        sh[tid] = mysum;
        __syncthreads();
        for (int d = 1; d < 256; d <<= 1) {
            int y = (tid >= d) ? sh[tid - d] : 0;
            __syncthreads();
            sh[tid] += y;
            __syncthreads();
        }
        int excl = sh[tid] - mysum;
        if (tid * 2     < lim) hist[i0]     = excl;
        if (tid * 2 + 1 < lim) hist[i0 + 1] = excl + v0;
        if (tid == 255) blockSum[blk] = sh[255];
    }

    grid.sync();   // (2)

    // ---- B2: block 0 exclusive-scans the 1024 chunk sums
    if (blk == 0) {
        int b0 = tid * 4;
        int w0 = blockSum[b0], w1 = blockSum[b0 + 1], w2 = blockSum[b0 + 2], w3 = blockSum[b0 + 3];
        int mysum = w0 + w1 + w2 + w3;
        sh[tid] = mysum;
        __syncthreads();
        for (int d = 1; d < 256; d <<= 1) {
            int y = (tid >= d) ? sh[tid - d] : 0;
            __syncthreads();
            sh[tid] += y;
            __syncthreads();
        }
        int excl = sh[tid] - mysum;
        blockSum[b0]     = excl;
        blockSum[b0 + 1] = excl + w0;
        blockSum[b0 + 2] = excl + w0 + w1;
        blockSum[b0 + 3] = excl + w0 + w1 + w2;
    }

    grid.sync();   // (3)

    // ---- C: scatter packed (src<<8 | localTgt); absolute offsets on the fly
    for (int b = tid; b < NBUCK; b += 256) {
        int idx = b * CNBLK + blk;
        sh2[b] = hist[idx] + blockSum[idx / SCCH];
    }
    __syncthreads();
    for (int e = e0 + tid; e < e1; e += 256) {
        int r = ei[e];          // source (< 2^17)
        int c = col[e];         // target
        int p = atomicAdd(&sh2[c >> CBSH], 1);
        tmp[p] = (r << CBSH) | (c & CBMASK);
    }

    grid.sync();   // (4)

    // ---- D: per-bucket fine counting sort (256 nodes/bucket, blocks 0..NBUCK-1)
    if (blk < NBUCK) {
        int i0 = blk * CNBLK;
        int start = hist[i0] + blockSum[i0 / SCCH];
        int end = (blk + 1 < NBUCK)
                    ? (hist[i0 + CNBLK] + blockSum[(i0 + CNBLK) / SCCH]) : E;
        sh[tid] = 0;
        __syncthreads();
        for (int p = start + tid; p < end; p += 256) atomicAdd(&sh[tmp[p] & CBMASK], 1);
        __syncthreads();
        int v = sh[tid];
        for (int d = 1; d < 256; d <<= 1) {
            int y = (tid >= d) ? sh[tid - d] : 0;
            __syncthreads();
            sh[tid] += y;
            __syncthreads();
        }
        int excl = sh[tid] - v;
        int node = (blk << CBSH) + tid;
        if (node < N) {
            cnt[node] = v;
            rowStart[node] = start + excl;
        }
        sh2[tid] = start + excl;
        __syncthreads();
        for (int p = start + tid; p < end; p += 256) {
            int pr = tmp[p];
            int slot = atomicAdd(&sh2[pr & CBMASK], 1);
            sortedRow[slot] = pr >> CBSH;
        }
        if (blk == 0 && tid == 0) rowStart[N] = E;
    }
}

// ================= fallback (round-3) CSR kernels =================
__global__ __launch_bounds__(256) void k_phase1(const int* __restrict__ col, int E,
                                                int* __restrict__ hist, int NBLK, int NBUCK) {
    __shared__ int h[MAXBUCK];
    int tid = threadIdx.x;
    h[tid] = 0;
    __syncthreads();
    int e0 = blockIdx.x * CHUNK;
    int e1 = min(e0 + CHUNK, E);
    for (int e = e0 + tid; e < e1; e += 256) atomicAdd(&h[col[e] >> BSH], 1);
    __syncthreads();
    if (tid < NBUCK) hist[tid * NBLK + blockIdx.x] = h[tid];
}

__global__ __launch_bounds__(1024) void k_scan_blk(int* __restrict__ a, int n,
                                                   int* __restrict__ blockSum) {
    __shared__ int s[1024];
    int t = threadIdx.x;
    int i = blockIdx.x * 1024 + t;
    int v = (i < n) ? a[i] : 0;
    s[t] = v;
    __syncthreads();
    for (int d = 1; d < 1024; d <<= 1) {
        int y = (t >= d) ? s[t - d] : 0;
        __syncthreads();
        s[t] += y;
        __syncthreads();
    }
    if (i < n) a[i] = s[t] - v;
    if (t == 1023) blockSum[blockIdx.x] = s[t];
}

__global__ __launch_bounds__(1024) void k_scan_top(int* __restrict__ blockSum, int nb) {
    __shared__ int s[1024];
    int t = threadIdx.x;
    int v = (t < nb) ? blockSum[t] : 0;
    s[t] = v;
    __syncthreads();
    for (int d = 1; d < 1024; d <<= 1) {
        int y = (t >= d) ? s[t - d] : 0;
        __syncthreads();
        s[t] += y;
        __syncthreads();
    }
    if (t < nb) blockSum[t] = s[t] - v;
}

__global__ __launch_bounds__(256) void k_scan_add(int* __restrict__ a,
                                                  const int* __restrict__ blockOff, int n) {
    int i = blockIdx.x * 256 + threadIdx.x;
    if (i < n) a[i] += blockOff[i >> 10];
}

__global__ __launch_bounds__(256) void k_phase3(const int* __restrict__ ei, int E,
                                                const int* __restrict__ offs, int NBLK, int NBUCK,
                                                int* __restrict__ tmp) {
    __shared__ int cur[MAXBUCK];
    int tid = threadIdx.x;
    if (tid < NBUCK) cur[tid] = offs[tid * NBLK + blockIdx.x];
    __syncthreads();
    int e0 = blockIdx.x * CHUNK;
    int e1 = min(e0 + CHUNK, E);
    for (int e = e0 + tid; e < e1; e += 256) {
        int r = ei[e];
        int c = ei[E + e];
        int p = atomicAdd(&cur[c >> BSH], 1);
        tmp[p] = (r << BSH) | (c & BMASK);
    }
}

__global__ __launch_bounds__(512) void k_fine(const int* __restrict__ tmp,
                                              const int* __restrict__ offs, int NBLK, int NBUCK,
                                              int N, int E,
                                              int* __restrict__ sortedRow,
                                              int* __restrict__ cnt,
                                              int* __restrict__ rowStart) {
    __shared__ int scnt[512];
    __shared__ int cur[512];
    int b = blockIdx.x;
    int t = threadIdx.x;
    int start = offs[b * NBLK];
    int end = (b + 1 < NBUCK) ? offs[(b + 1) * NBLK] : E;

    scnt[t] = 0;
    __syncthreads();
    for (int p = start + t; p < end; p += 512) atomicAdd(&scnt[tmp[p] & BMASK], 1);
    __syncthreads();
    int v = scnt[t];
    for (int d = 1; d < 512; d <<= 1) {
        int y = (t >= d) ? scnt[t - d] : 0;
        __syncthreads();
        scnt[t] += y;
        __syncthreads();
    }
    int excl = scnt[t] - v;
    int node = (b << BSH) + t;
    if (node < N) {
        cnt[node] = v;
        rowStart[node] = start + excl;
    }
    cur[t] = start + excl;
    __syncthreads();
    for (int p = start + t; p < end; p += 512) {
        int pr = tmp[p];
        int slot = atomicAdd(&cur[pr & BMASK], 1);
        sortedRow[slot] = pr >> BSH;
    }
    if (b == NBUCK - 1 && t == 0) rowStart[N] = E;
}

// ---------- g = fp16( dinv * (x @ Wc^T) ) via MFMA 16x16x32 f16, 1 barrier/tile
__global__ __launch_bounds__(256) void k_gemm_mfma(const float* __restrict__ x,
                                                   const _Float16* __restrict__ Bfrag,
                                                   const int* __restrict__ cnt,
                                                   _Float16* __restrict__ g, int nrows) {
    __shared__ __align__(16) _Float16 xs[2][16 * AROW];
    int tid  = threadIdx.x;
    int lane = tid & 63;
    int w    = tid >> 6;      // wave 0..3
    int quad = lane >> 4;
    int lcol = lane & 15;

    const half8* Bv = (const half8*)Bfrag;
    half8 b0[8], b1[8];
#pragma unroll
    for (int kk = 0; kk < 8; ++kk) {
        b0[kk] = Bv[(w * 8 + kk) * 64 + lane];
        b1[kk] = Bv[((w + 4) * 8 + kk) * 64 + lane];
    }

    long base = (long)blockIdx.x * (16 * MT);
    for (int t = 0; t < MT; ++t) {
        long m0 = base + t * 16;
        _Float16* xb = xs[t & 1];
        // WAR-safe: barrier at tile t-1 guaranteed reads of this buffer done.
        const float4* xv = (const float4*)(x + m0 * KDIM);
#pragma unroll
        for (int ii = 0; ii < 4; ++ii) {
            int idx = tid + ii * 256;        // 16 rows x 64 float4
            int m = idx >> 6, k4 = idx & 63;
            float4 v = xv[idx];
            half4v hv = { (_Float16)v.x, (_Float16)v.y, (_Float16)v.z, (_Float16)v.w };
            *(half4v*)&xb[m * AROW + k4 * 4] = hv;
        }
        __syncthreads();

        float4v acc0 = {0.f, 0.f, 0.f, 0.f}, acc1 = {0.f, 0.f, 0.f, 0.f};
#pragma unroll
        for (int kk = 0; kk < 8; ++kk) {
            half8 a = *(const half8*)(&xb[lcol * AROW + kk * 32 + quad * 8]);
            acc0 = __builtin_amdgcn_mfma_f32_16x16x32_f16(a, b0[kk], acc0, 0, 0, 0);
            acc1 = __builtin_amdgcn_mfma_f32_16x16x32_f16(a, b1[kk], acc1, 0, 0, 0);
        }

        // C/D layout: col = lane&15, row = quad*4 + reg
#pragma unroll
        for (int r = 0; r < 4; ++r) {
            long node = m0 + quad * 4 + r;
            float di = rsqrtf((float)(cnt[node] + 1));   // deg = cnt + self-loop
            g[node * NDIM + w * 16 + lcol]        = (_Float16)(acc0[r] * di);
            g[node * NDIM + (w + 4) * 16 + lcol]  = (_Float16)(acc1[r] * di);
        }
    }
}

// ---------- gather + scale + bias + row L2-normalize
// One WAVE per node. Each 16-lane group owns one EDGE; each lane loads a
// 16B half8 slice -> one global_load_dwordx4 fetches 4 complete 256B rows.
__global__ __launch_bounds__(256) void k_gather(const _Float16* __restrict__ g,
                                                const int* __restrict__ rowStart,
                                                const int* __restrict__ sortedRow,
                                                const int* __restrict__ cnt,
                                                const float* __restrict__ bg,
                                                float* __restrict__ out) {
    int lane = threadIdx.x & 63;
    int i = blockIdx.x * 4 + (threadIdx.x >> 6);   // node, N divisible by 4
    const int s = rowStart[i];
    const int e = rowStart[i + 1];
    const int g4  = lane >> 4;   // edge slot within wave: 0..3
    const int r16 = lane & 15;   // dim slot: halfs [r16*8, r16*8+8)

    const half8* __restrict__ gv = (const half8*)g;  // 16 half8 per row

    float acc[8];
#pragma unroll
    for (int j = 0; j < 8; ++j) acc[j] = 0.f;

    int p = s;
    // main: 16 edges per iteration, 4x dwordx4 in flight (4KB/wave)
    for (; p + 16 <= e; p += 16) {
        int r0 = sortedRow[p + g4];
        int r1 = sortedRow[p + 4 + g4];
        int r2 = sortedRow[p + 8 + g4];
        int r3 = sortedRow[p + 12 + g4];
        half8 v0 = gv[(size_t)r0 * 16 + r16];
        half8 v1 = gv[(size_t)r1 * 16 + r16];
        half8 v2 = gv[(size_t)r2 * 16 + r16];
        half8 v3 = gv[(size_t)r3 * 16 + r16];
#pragma unroll
        for (int j = 0; j < 8; ++j)
            acc[j] += ((float)v0[j] + (float)v1[j]) + ((float)v2[j] + (float)v3[j]);
    }
    // 4 edges per iteration
    for (; p + 4 <= e; p += 4) {
        int r0 = sortedRow[p + g4];
        half8 v0 = gv[(size_t)r0 * 16 + r16];
#pragma unroll
        for (int j = 0; j < 8; ++j) acc[j] += (float)v0[j];
    }
    // tail: 1..3 edges, predicated per edge-slot group
    if (p + g4 < e) {
        int r0 = sortedRow[p + g4];
        half8 v0 = gv[(size_t)r0 * 16 + r16];
#pragma unroll
        for (int j = 0; j < 8; ++j) acc[j] += (float)v0[j];
    }

    // fold the 4 edge-slot groups (result replicated in all lanes)
#pragma unroll
    for (int j = 0; j < 8; ++j) {
        acc[j] += __shfl_xor(acc[j], 16);
        acc[j] += __shfl_xor(acc[j], 32);
    }

    // self-loop message (added once, post-fold)
    half8 sv = gv[(size_t)i * 16 + r16];
#pragma unroll
    for (int j = 0; j < 8; ++j) acc[j] += (float)sv[j];

    float di = rsqrtf((float)(cnt[i] + 1));
    float4 b0 = ((const float4*)bg)[r16 * 2];
    float4 b1 = ((const float4*)bg)[r16 * 2 + 1];
    float v[8];
    v[0] = fmaf(di, acc[0], b0.x);
    v[1] = fmaf(di, acc[1], b0.y);
    v[2] = fmaf(di, acc[2], b0.z);
    v[3] = fmaf(di, acc[3], b0.w);
    v[4] = fmaf(di, acc[4], b1.x);
    v[5] = fmaf(di, acc[5], b1.y);
    v[6] = fmaf(di, acc[6], b1.z);
    v[7] = fmaf(di, acc[7], b1.w);

    float sq = 0.f;
#pragma unroll
    for (int j = 0; j < 8; ++j) sq += v[j] * v[j];
    sq += __shfl_xor(sq, 1);
    sq += __shfl_xor(sq, 2);
    sq += __shfl_xor(sq, 4);
    sq += __shfl_xor(sq, 8);
    float scale = 1.0f / fmaxf(sqrtf(sq), 1e-12f);

    if (g4 == 0) {
        float4 o0 = make_float4(v[0] * scale, v[1] * scale, v[2] * scale, v[3] * scale);
        float4 o1 = make_float4(v[4] * scale, v[5] * scale, v[6] * scale, v[7] * scale);
        ((float4*)out)[(size_t)i * 32 + r16 * 2]     = o0;
        ((float4*)out)[(size_t)i * 32 + r16 * 2 + 1] = o1;
    }
}

extern "C" void kernel_launch(void* const* d_in, const int* in_sizes, int n_in,
                              void* d_out, int out_size, void* d_ws, size_t ws_size,
                              hipStream_t stream) {
    const float* x  = (const float*)d_in[0];
    const int*   ei = (const int*)  d_in[1];
    const float* Wp = (const float*)d_in[2];
    const float* Wg = (const float*)d_in[3];
    const float* bg = (const float*)d_in[4];
    float* out = (float*)d_out;

    const int N = in_sizes[0] / KDIM;   // 100000
    const int E = in_sizes[1] / 2;      // 1600000

    // cooperative CSR sizes
    const int CNBUCK = (N + CBMASK) >> CBSH;     // 391
    const int CNE    = CNBUCK * CNBLK;           // 400384

    // fallback CSR sizes
    const int NBLK  = (E + CHUNK - 1) / CHUNK;   // 500
    const int NBUCK = (N + BMASK) >> BSH;        // 196
    const int NE    = NBLK * NBUCK;              // 98000
    const int NSB   = (NE + 1023) >> 10;         // 96

    const int histN = (CNE > NE) ? CNE : NE;

    // carve workspace (256B aligned)
    char* p = (char*)d_ws;
    auto carve = [&](size_t bytes) { void* r = (void*)p; p += (bytes + 255) & ~(size_t)255; return r; };
    _Float16* g      = (_Float16*)carve((size_t)N * NDIM * 2);  // 25.6 MB
    int*   sortedRow = (int*)  carve((size_t)E * 4);            // 6.4 MB
    int*   tmp       = (int*)  carve((size_t)E * 4);            // 6.4 MB (packed)
    _Float16* Bfrag  = (_Float16*)carve((size_t)KDIM * NDIM * 2);
    int*   cnt       = (int*)  carve((size_t)N * 4);
    int*   rowStart  = (int*)  carve((size_t)(N + 1) * 4);
    int*   hist      = (int*)  carve((size_t)histN * 4);
    int*   blockSum  = (int*)  carve((size_t)1024 * 4);

    hipLaunchKernelGGL(k_combine_w, dim3(NDIM), dim3(KDIM), 0, stream, Wp, Wg, Bfrag);

    // cooperative single-kernel CSR build, with multi-kernel fallback
    {
        const int* eiA = ei; int Ev = E, Nv = N;
        int* tmpA = tmp; int* srA = sortedRow; int* cntA = cnt; int* rsA = rowStart;
        int* histA = hist; int* bsA = blockSum;
        void* cargs[] = { (void*)&eiA, (void*)&Ev, (void*)&Nv, (void*)&tmpA, (void*)&srA,
                          (void*)&cntA, (void*)&rsA, (void*)&histA, (void*)&bsA };
        hipError_t cerr = hipLaunchCooperativeKernel((void*)k_csr, dim3(CNBLK), dim3(256),
                                                     cargs, 0, stream);
        if (cerr != hipSuccess) {
            hipLaunchKernelGGL(k_phase1, dim3(NBLK), dim3(256), 0, stream, ei + E, E, hist, NBLK, NBUCK);
            hipLaunchKernelGGL(k_scan_blk, dim3(NSB), dim3(1024), 0, stream, hist, NE, blockSum);
            hipLaunchKernelGGL(k_scan_top, dim3(1), dim3(1024), 0, stream, blockSum, NSB);
            hipLaunchKernelGGL(k_scan_add, dim3((NE + 255) / 256), dim3(256), 0, stream, hist, blockSum, NE);
            hipLaunchKernelGGL(k_phase3, dim3(NBLK), dim3(256), 0, stream, ei, E, hist, NBLK, NBUCK, tmp);
            hipLaunchKernelGGL(k_fine, dim3(NBUCK), dim3(512), 0, stream, tmp, hist, NBLK, NBUCK, N, E,
                               sortedRow, cnt, rowStart);
        }
    }

    hipLaunchKernelGGL(k_gemm_mfma, dim3(N / (16 * MT)), dim3(256), 0, stream, x, Bfrag, cnt, g, N);
    hipLaunchKernelGGL(k_gather, dim3(N / 4), dim3(256), 0, stream,
                       g, rowStart, sortedRow, cnt, bg, out);
}

// Round 5
// 313.169 us; speedup vs baseline: 2.4801x; 2.4801x over previous
//
#include <hip/hip_runtime.h>
#include <hip/hip_fp16.h>

#define NDIM 128     // OUT_DIM
#define KDIM 256     // IN_DIM
#define MT 5         // M-tiles (of 16 rows) per GEMM block
#define AROW 264     // LDS A-row stride in halfs (16B-aligned, breaks pow2)
#define CHUNK 3200   // edges per phase1/phase3 block (500 blocks)
#define BSH 8        // bucket = 256 nodes
#define BMASK 255
#define MAXBUCK 400  // >= NBUCK = ceil(N/256) = 391
#define FTH 512      // k_fine threads

typedef _Float16 half8 __attribute__((ext_vector_type(8)));
typedef _Float16 half4v __attribute__((ext_vector_type(4)));
typedef _Float16 half2v __attribute__((ext_vector_type(2)));
typedef float float4v __attribute__((ext_vector_type(4)));

#if __has_builtin(__builtin_amdgcn_fdot2)
#define HAS_FDOT2 1
#else
#define HAS_FDOT2 0
#endif

// ---------- Wc = Wg @ Wp, written directly in MFMA B-fragment layout (fp16)
__global__ void k_combine_w(const float* __restrict__ Wp, const float* __restrict__ Wg,
                            _Float16* __restrict__ Bfrag) {
    int o = blockIdx.x;      // n: 0..127
    int i = threadIdx.x;     // k: 0..255
    float acc = 0.f;
#pragma unroll 4
    for (int k = 0; k < 128; ++k) acc = fmaf(Wg[o * 128 + k], Wp[k * 256 + i], acc);
    int kk = i >> 5, r = i & 31, quad = r >> 3, j = r & 7;
    int ntile = o >> 4, lanen = o & 15, lane = quad * 16 + lanen;
    Bfrag[(((ntile * 8 + kk) * 64) + lane) * 8 + j] = (_Float16)acc;
}

// ---------- CSR pass 1: per-block coarse histogram (bucket = tgt>>8)
__global__ __launch_bounds__(256) void k_phase1(const int* __restrict__ col, int E,
                                                int* __restrict__ hist, int NBLK, int NBUCK) {
    __shared__ int h[MAXBUCK];
    int tid = threadIdx.x;
    for (int b = tid; b < MAXBUCK; b += 256) h[b] = 0;
    __syncthreads();
    int e0 = blockIdx.x * CHUNK;
    int e1 = min(e0 + CHUNK, E);
    for (int e = e0 + tid; e < e1; e += 256) atomicAdd(&h[col[e] >> BSH], 1);
    __syncthreads();
    for (int b = tid; b < NBUCK; b += 256) hist[b * NBLK + blockIdx.x] = h[b];
}

// ---------- CSR pass 2a: in-place per-1024-chunk exclusive scan of hist
__global__ __launch_bounds__(1024) void k_scan_blk(int* __restrict__ a, int n,
                                                   int* __restrict__ blockSum) {
    __shared__ int s[1024];
    int t = threadIdx.x;
    int i = blockIdx.x * 1024 + t;
    int v = (i < n) ? a[i] : 0;
    s[t] = v;
    __syncthreads();
    for (int d = 1; d < 1024; d <<= 1) {
        int y = (t >= d) ? s[t - d] : 0;
        __syncthreads();
        s[t] += y;
        __syncthreads();
    }
    if (i < n) a[i] = s[t] - v;       // exclusive, chunk-local
    if (t == 1023) blockSum[blockIdx.x] = s[t];
}

// ---------- CSR pass 2b: exclusive scan of chunk sums (nb <= 1024)
__global__ __launch_bounds__(1024) void k_scan_top(int* __restrict__ blockSum, int nb) {
    __shared__ int s[1024];
    int t = threadIdx.x;
    int v = (t < nb) ? blockSum[t] : 0;
    s[t] = v;
    __syncthreads();
    for (int d = 1; d < 1024; d <<= 1) {
        int y = (t >= d) ? s[t - d] : 0;
        __syncthreads();
        s[t] += y;
        __syncthreads();
    }
    if (t < nb) blockSum[t] = s[t] - v;
}

// ---------- CSR pass 2c: add chunk offsets -> absolute exclusive scan
__global__ __launch_bounds__(256) void k_scan_add(int* __restrict__ a,
                                                  const int* __restrict__ blockOff, int n) {
    int i = blockIdx.x * 256 + threadIdx.x;
    if (i < n) a[i] += blockOff[i >> 10];
}

// ---------- CSR pass 3: scatter packed (src<<8 | localTgt) into per-(bucket,block) runs
__global__ __launch_bounds__(256) void k_phase3(const int* __restrict__ ei, int E,
                                                const int* __restrict__ offs, int NBLK, int NBUCK,
                                                int* __restrict__ tmp) {
    __shared__ int cur[MAXBUCK];
    int tid = threadIdx.x;
    for (int b = tid; b < NBUCK; b += 256) cur[b] = offs[b * NBLK + blockIdx.x];
    __syncthreads();
    int e0 = blockIdx.x * CHUNK;
    int e1 = min(e0 + CHUNK, E);
    for (int e = e0 + tid; e < e1; e += 256) {
        int r = ei[e];          // source (< 2^17)
        int c = ei[E + e];      // target
        int p = atomicAdd(&cur[c >> BSH], 1);
        tmp[p] = (r << BSH) | (c & BMASK);
    }
}

// ---------- CSR pass 4: per-bucket fine counting sort (256 nodes/bucket, 512 thr)
__global__ __launch_bounds__(FTH) void k_fine(const int* __restrict__ tmp,
                                              const int* __restrict__ offs, int NBLK, int NBUCK,
                                              int N, int E,
                                              int* __restrict__ sortedRow,
                                              int* __restrict__ cnt,
                                              int* __restrict__ rowStart) {
    __shared__ int scnt[256];
    __shared__ int cur[256];
    int b = blockIdx.x;
    int t = threadIdx.x;
    int start = offs[b * NBLK];
    int end = (b + 1 < NBUCK) ? offs[(b + 1) * NBLK] : E;

    if (t < 256) scnt[t] = 0;
    __syncthreads();
    for (int p = start + t; p < end; p += FTH) atomicAdd(&scnt[tmp[p] & BMASK], 1);
    __syncthreads();
    int v = (t < 256) ? scnt[t] : 0;
    // inclusive scan over 256 entries (8 steps), 512-thread-safe barriers
    for (int d = 1; d < 256; d <<= 1) {
        int y = (t >= d && t < 256) ? scnt[t - d] : 0;
        __syncthreads();
        if (t < 256) scnt[t] += y;
        __syncthreads();
    }
    if (t < 256) {
        int excl = scnt[t] - v;
        int node = (b << BSH) + t;
        if (node < N) {
            cnt[node] = v;
            rowStart[node] = start + excl;
        }
        cur[t] = start + excl;
    }
    __syncthreads();
    for (int p = start + t; p < end; p += FTH) {
        int pr = tmp[p];
        int slot = atomicAdd(&cur[pr & BMASK], 1);
        sortedRow[slot] = pr >> BSH;
    }
    if (b == NBUCK - 1 && t == 0) rowStart[N] = E;
}

// ---------- g = fp16( dinv * (x @ Wc^T) ) via MFMA 16x16x32 f16, 1 barrier/tile
__global__ __launch_bounds__(256) void k_gemm_mfma(const float* __restrict__ x,
                                                   const _Float16* __restrict__ Bfrag,
                                                   const int* __restrict__ cnt,
                                                   _Float16* __restrict__ g, int nrows) {
    __shared__ __align__(16) _Float16 xs[2][16 * AROW];
    int tid  = threadIdx.x;
    int lane = tid & 63;
    int w    = tid >> 6;      // wave 0..3
    int quad = lane >> 4;
    int lcol = lane & 15;

    const half8* Bv = (const half8*)Bfrag;
    half8 b0[8], b1[8];
#pragma unroll
    for (int kk = 0; kk < 8; ++kk) {
        b0[kk] = Bv[(w * 8 + kk) * 64 + lane];
        b1[kk] = Bv[((w + 4) * 8 + kk) * 64 + lane];
    }

    long base = (long)blockIdx.x * (16 * MT);
    for (int t = 0; t < MT; ++t) {
        long m0 = base + t * 16;
        _Float16* xb = xs[t & 1];
        // WAR-safe: barrier at tile t-1 guaranteed reads of this buffer done.
        const float4* xv = (const float4*)(x + m0 * KDIM);
#pragma unroll
        for (int ii = 0; ii < 4; ++ii) {
            int idx = tid + ii * 256;        // 16 rows x 64 float4
            int m = idx >> 6, k4 = idx & 63;
            float4 v = xv[idx];
            half4v hv = { (_Float16)v.x, (_Float16)v.y, (_Float16)v.z, (_Float16)v.w };
            *(half4v*)&xb[m * AROW + k4 * 4] = hv;
        }
        __syncthreads();

        float4v acc0 = {0.f, 0.f, 0.f, 0.f}, acc1 = {0.f, 0.f, 0.f, 0.f};
#pragma unroll
        for (int kk = 0; kk < 8; ++kk) {
            half8 a = *(const half8*)(&xb[lcol * AROW + kk * 32 + quad * 8]);
            acc0 = __builtin_amdgcn_mfma_f32_16x16x32_f16(a, b0[kk], acc0, 0, 0, 0);
            acc1 = __builtin_amdgcn_mfma_f32_16x16x32_f16(a, b1[kk], acc1, 0, 0, 0);
        }

        // C/D layout: col = lane&15, row = quad*4 + reg
#pragma unroll
        for (int r = 0; r < 4; ++r) {
            long node = m0 + quad * 4 + r;
            float di = rsqrtf((float)(cnt[node] + 1));   // deg = cnt + self-loop
            g[node * NDIM + w * 16 + lcol]        = (_Float16)(acc0[r] * di);
            g[node * NDIM + (w + 4) * 16 + lcol]  = (_Float16)(acc1[r] * di);
        }
    }
}

// ---------- gather + scale + bias + row L2-normalize
// One WAVE per node. Each 16-lane group owns one EDGE; each lane loads a
// 16B half8 slice -> one global_load_dwordx4 fetches 4 complete 256B rows.
// Message accumulation pairs two edges per half2 and uses v_dot2_f32_f16.
__global__ __launch_bounds__(256) void k_gather(const _Float16* __restrict__ g,
                                                const int* __restrict__ rowStart,
                                                const int* __restrict__ sortedRow,
                                                const int* __restrict__ cnt,
                                                const float* __restrict__ bg,
                                                float* __restrict__ out) {
    int lane = threadIdx.x & 63;
    int i = blockIdx.x * 4 + (threadIdx.x >> 6);   // node, N divisible by 4
    const int s = rowStart[i];
    const int e = rowStart[i + 1];
    const int g4  = lane >> 4;   // edge slot within wave: 0..3
    const int r16 = lane & 15;   // dim slot: halfs [r16*8, r16*8+8)

    const half8* __restrict__ gv = (const half8*)g;  // 16 half8 per row

    float acc[8];
#pragma unroll
    for (int j = 0; j < 8; ++j) acc[j] = 0.f;

#if HAS_FDOT2
    const half2v one2 = { (_Float16)1.0f, (_Float16)1.0f };
#endif

    int p = s;
    // main: 16 edges per iteration, 4x dwordx4 in flight (4KB/wave)
    for (; p + 16 <= e; p += 16) {
        int r0 = sortedRow[p + g4];
        int r1 = sortedRow[p + 4 + g4];
        int r2 = sortedRow[p + 8 + g4];
        int r3 = sortedRow[p + 12 + g4];
        half8 v0 = gv[(size_t)r0 * 16 + r16];
        half8 v1 = gv[(size_t)r1 * 16 + r16];
        half8 v2 = gv[(size_t)r2 * 16 + r16];
        half8 v3 = gv[(size_t)r3 * 16 + r16];
#if HAS_FDOT2
#pragma unroll
        for (int j = 0; j < 8; ++j) {
            half2v a = { v0[j], v1[j] };
            half2v b = { v2[j], v3[j] };
            acc[j] = __builtin_amdgcn_fdot2(a, one2,
                     __builtin_amdgcn_fdot2(b, one2, acc[j], false), false);
        }
#else
#pragma unroll
        for (int j = 0; j < 8; ++j)
            acc[j] += ((float)v0[j] + (float)v1[j]) + ((float)v2[j] + (float)v3[j]);
#endif
    }
    // 8 edges
    if (p + 8 <= e) {
        int r0 = sortedRow[p + g4];
        int r1 = sortedRow[p + 4 + g4];
        half8 v0 = gv[(size_t)r0 * 16 + r16];
        half8 v1 = gv[(size_t)r1 * 16 + r16];
#if HAS_FDOT2
#pragma unroll
        for (int j = 0; j < 8; ++j) {
            half2v a = { v0[j], v1[j] };
            acc[j] = __builtin_amdgcn_fdot2(a, one2, acc[j], false);
        }
#else
#pragma unroll
        for (int j = 0; j < 8; ++j) acc[j] += (float)v0[j] + (float)v1[j];
#endif
        p += 8;
    }
    // 4 edges
    if (p + 4 <= e) {
        int r0 = sortedRow[p + g4];
        half8 v0 = gv[(size_t)r0 * 16 + r16];
#pragma unroll
        for (int j = 0; j < 8; ++j) acc[j] += (float)v0[j];
        p += 4;
    }
    // tail: 1..3 edges, predicated per edge-slot group
    if (p + g4 < e) {
        int r0 = sortedRow[p + g4];
        half8 v0 = gv[(size_t)r0 * 16 + r16];
#pragma unroll
        for (int j = 0; j < 8; ++j) acc[j] += (float)v0[j];
    }

    // fold the 4 edge-slot groups (result replicated in all lanes)
#pragma unroll
    for (int j = 0; j < 8; ++j) {
        acc[j] += __shfl_xor(acc[j], 16);
        acc[j] += __shfl_xor(acc[j], 32);
    }

    // self-loop message (added once, post-fold)
    half8 sv = gv[(size_t)i * 16 + r16];
#pragma unroll
    for (int j = 0; j < 8; ++j) acc[j] += (float)sv[j];

    float di = rsqrtf((float)(cnt[i] + 1));
    float4 b0 = ((const float4*)bg)[r16 * 2];
    float4 b1 = ((const float4*)bg)[r16 * 2 + 1];
    float v[8];
    v[0] = fmaf(di, acc[0], b0.x);
    v[1] = fmaf(di, acc[1], b0.y);
    v[2] = fmaf(di, acc[2], b0.z);
    v[3] = fmaf(di, acc[3], b0.w);
    v[4] = fmaf(di, acc[4], b1.x);
    v[5] = fmaf(di, acc[5], b1.y);
    v[6] = fmaf(di, acc[6], b1.z);
    v[7] = fmaf(di, acc[7], b1.w);

    float sq = 0.f;
#pragma unroll
    for (int j = 0; j < 8; ++j) sq += v[j] * v[j];
    sq += __shfl_xor(sq, 1);
    sq += __shfl_xor(sq, 2);
    sq += __shfl_xor(sq, 4);
    sq += __shfl_xor(sq, 8);
    float scale = 1.0f / fmaxf(sqrtf(sq), 1e-12f);

    if (g4 == 0) {
        float4 o0 = make_float4(v[0] * scale, v[1] * scale, v[2] * scale, v[3] * scale);
        float4 o1 = make_float4(v[4] * scale, v[5] * scale, v[6] * scale, v[7] * scale);
        ((float4*)out)[(size_t)i * 32 + r16 * 2]     = o0;
        ((float4*)out)[(size_t)i * 32 + r16 * 2 + 1] = o1;
    }
}

extern "C" void kernel_launch(void* const* d_in, const int* in_sizes, int n_in,
                              void* d_out, int out_size, void* d_ws, size_t ws_size,
                              hipStream_t stream) {
    const float* x  = (const float*)d_in[0];
    const int*   ei = (const int*)  d_in[1];
    const float* Wp = (const float*)d_in[2];
    const float* Wg = (const float*)d_in[3];
    const float* bg = (const float*)d_in[4];
    float* out = (float*)d_out;

    const int N = in_sizes[0] / KDIM;   // 100000
    const int E = in_sizes[1] / 2;      // 1600000

    const int NBLK  = (E + CHUNK - 1) / CHUNK;   // 500
    const int NBUCK = (N + BMASK) >> BSH;        // 391
    const int NE    = NBLK * NBUCK;              // 195500
    const int NSB   = (NE + 1023) >> 10;         // 191 scan chunks

    // carve workspace (256B aligned)
    char* p = (char*)d_ws;
    auto carve = [&](size_t bytes) { void* r = (void*)p; p += (bytes + 255) & ~(size_t)255; return r; };
    _Float16* g      = (_Float16*)carve((size_t)N * NDIM * 2);  // 25.6 MB
    int*   sortedRow = (int*)  carve((size_t)E * 4);            // 6.4 MB
    int*   tmp       = (int*)  carve((size_t)E * 4);            // 6.4 MB (packed)
    _Float16* Bfrag  = (_Float16*)carve((size_t)KDIM * NDIM * 2);
    int*   cnt       = (int*)  carve((size_t)N * 4);
    int*   rowStart  = (int*)  carve((size_t)(N + 1) * 4);
    int*   hist      = (int*)  carve((size_t)NE * 4);
    int*   blockSum  = (int*)  carve((size_t)1024 * 4);

    hipLaunchKernelGGL(k_combine_w, dim3(NDIM), dim3(KDIM), 0, stream, Wp, Wg, Bfrag);
    hipLaunchKernelGGL(k_phase1, dim3(NBLK), dim3(256), 0, stream, ei + E, E, hist, NBLK, NBUCK);
    hipLaunchKernelGGL(k_scan_blk, dim3(NSB), dim3(1024), 0, stream, hist, NE, blockSum);
    hipLaunchKernelGGL(k_scan_top, dim3(1), dim3(1024), 0, stream, blockSum, NSB);
    hipLaunchKernelGGL(k_scan_add, dim3((NE + 255) / 256), dim3(256), 0, stream, hist, blockSum, NE);
    hipLaunchKernelGGL(k_phase3, dim3(NBLK), dim3(256), 0, stream, ei, E, hist, NBLK, NBUCK, tmp);
    hipLaunchKernelGGL(k_fine, dim3(NBUCK), dim3(FTH), 0, stream, tmp, hist, NBLK, NBUCK, N, E,
                       sortedRow, cnt, rowStart);
    hipLaunchKernelGGL(k_gemm_mfma, dim3(N / (16 * MT)), dim3(256), 0, stream, x, Bfrag, cnt, g, N);
    hipLaunchKernelGGL(k_gather, dim3(N / 4), dim3(256), 0, stream,
                       g, rowStart, sortedRow, cnt, bg, out);
}

// Round 6
// 296.629 us; speedup vs baseline: 2.6184x; 1.0558x over previous
//
#include <hip/hip_runtime.h>
#include <hip/hip_fp16.h>

#define NDIM 128     // OUT_DIM
#define KDIM 256     // IN_DIM
#define MT 5         // M-tiles (of 16 rows) per GEMM block
#define AROW 264     // LDS A-row stride in halfs (16B-aligned, breaks pow2)
#define CHUNK 3200   // edges per phase1/phase3 block (500 blocks)
#define BSH 9        // bucket = 512 nodes (round-3 proven best)
#define BMASK 511
#define MAXBUCK 256  // >= NBUCK = ceil(N/512) = 196
#define FTH 512      // k_fine threads
#define ECAP 12032   // k_fine LDS staging capacity (48KB); mean run 8192, max ~8.8K
#define SFLAG 0x40000000

typedef _Float16 half8 __attribute__((ext_vector_type(8)));
typedef _Float16 half4v __attribute__((ext_vector_type(4)));
typedef _Float16 half2v __attribute__((ext_vector_type(2)));
typedef float float4v __attribute__((ext_vector_type(4)));

#if __has_builtin(__builtin_amdgcn_fdot2)
#define HAS_FDOT2 1
#else
#define HAS_FDOT2 0
#endif

// ---------- K1: fused [phase1 histogram | combine_w], block-range split.
// blocks 0..NBLK-1: per-block coarse histogram (bucket = tgt>>9)
// blocks NBLK..NBLK+127: Wc = Wg @ Wp in MFMA B-fragment layout
// block 0 additionally zeroes the scan-lookback flags (replay-safe).
__global__ __launch_bounds__(256) void k_prep(const float* __restrict__ Wp,
                                              const float* __restrict__ Wg,
                                              _Float16* __restrict__ Bfrag,
                                              const int* __restrict__ ei, int E,
                                              int* __restrict__ hist, int NBLK, int NBUCK,
                                              int* __restrict__ partials, int NSB) {
    __shared__ int h[MAXBUCK];
    int tid = threadIdx.x;
    int blk = blockIdx.x;
    if (blk < NBLK) {
        // ---- phase1
        if (blk == 0 && tid < 128) {            // zero lookback flags (NSB <= 128)
            partials[tid] = 0;
        }
        const int* __restrict__ col = ei + E;
        h[tid] = 0;
        __syncthreads();
        int e0 = blk * CHUNK;
        int e1 = min(e0 + CHUNK, E);
        for (int e = e0 + tid; e < e1; e += 256) atomicAdd(&h[col[e] >> BSH], 1);
        __syncthreads();
        if (tid < NBUCK) hist[tid * NBLK + blk] = h[tid];
    } else {
        // ---- combine_w
        int o = blk - NBLK;      // n: 0..127
        int i = tid;             // k: 0..255
        float acc = 0.f;
#pragma unroll 4
        for (int k = 0; k < 128; ++k) acc = fmaf(Wg[o * 128 + k], Wp[k * 256 + i], acc);
        int kk = i >> 5, r = i & 31, quad = r >> 3, j = r & 7;
        int ntile = o >> 4, lanen = o & 15, lane = quad * 16 + lanen;
        Bfrag[(((ntile * 8 + kk) * 64) + lane) * 8 + j] = (_Float16)acc;
    }
}

// ---------- K2: single-kernel exclusive scan via aggregate lookback.
// 96 blocks x 1024 threads, all co-resident (96 << 256 CUs) -> spin is safe.
__global__ __launch_bounds__(1024) void k_scan_lb(int* __restrict__ a, int n,
                                                  int* __restrict__ partials) {
    __shared__ int s[1024];
    int t = threadIdx.x;
    int blk = blockIdx.x;
    int i = blk * 1024 + t;
    int v = (i < n) ? a[i] : 0;
    s[t] = v;
    __syncthreads();
    for (int d = 1; d < 1024; d <<= 1) {
        int y = (t >= d) ? s[t - d] : 0;
        __syncthreads();
        s[t] += y;
        __syncthreads();
    }
    int myincl = s[t];
    int total = s[1023];
    // publish this chunk's aggregate (device scope, release)
    if (t == 0)
        __hip_atomic_store(&partials[blk], total | SFLAG,
                           __ATOMIC_RELEASE, __HIP_MEMORY_SCOPE_AGENT);
    // lookback: thread t (t < blk) waits for chunk t's aggregate
    int contrib = 0;
    if (t < blk) {
        int pv;
        do {
            pv = __hip_atomic_load(&partials[t], __ATOMIC_ACQUIRE,
                                   __HIP_MEMORY_SCOPE_AGENT);
        } while (!(pv & SFLAG));
        contrib = pv & ~SFLAG;
    }
    __syncthreads();
    s[t] = contrib;
    __syncthreads();
    for (int d = 512; d > 0; d >>= 1) {
        if (t < d) s[t] += s[t + d];
        __syncthreads();
    }
    int excl = s[0];
    if (i < n) a[i] = myincl - v + excl;    // absolute exclusive scan
}

// ---------- CSR pass 3: scatter packed (src<<9 | localTgt) into per-(bucket,block) runs
__global__ __launch_bounds__(256) void k_phase3(const int* __restrict__ ei, int E,
                                                const int* __restrict__ offs, int NBLK, int NBUCK,
                                                int* __restrict__ tmp) {
    __shared__ int cur[MAXBUCK];
    int tid = threadIdx.x;
    if (tid < NBUCK) cur[tid] = offs[tid * NBLK + blockIdx.x];
    __syncthreads();
    int e0 = blockIdx.x * CHUNK;
    int e1 = min(e0 + CHUNK, E);
    for (int e = e0 + tid; e < e1; e += 256) {
        int r = ei[e];          // source (< 2^17)
        int c = ei[E + e];      // target
        int p = atomicAdd(&cur[c >> BSH], 1);
        tmp[p] = (r << BSH) | (c & BMASK);
    }
}

// ---------- CSR pass 4: per-bucket fine counting sort (512 nodes/bucket),
// single-pass: bucket run staged in LDS (reads tmp once), fallback if oversized.
__global__ __launch_bounds__(FTH, 1) void k_fine(const int* __restrict__ tmp,
                                                 const int* __restrict__ offs, int NBLK, int NBUCK,
                                                 int N, int E,
                                                 int* __restrict__ sortedRow,
                                                 int* __restrict__ cnt,
                                                 int* __restrict__ rowStart) {
    __shared__ int scnt[512];
    __shared__ int cur[512];
    __shared__ int ec[ECAP];
    int b = blockIdx.x;
    int t = threadIdx.x;
    int start = offs[b * NBLK];
    int end = (b + 1 < NBUCK) ? offs[(b + 1) * NBLK] : E;
    int len = end - start;

    scnt[t] = 0;
    __syncthreads();
    if (len <= ECAP) {
        // stage + histogram in one pass
        for (int p = t; p < len; p += FTH) {
            int v = tmp[start + p];
            ec[p] = v;
            atomicAdd(&scnt[v & BMASK], 1);
        }
        __syncthreads();
        int v = scnt[t];
        for (int d = 1; d < 512; d <<= 1) {
            int y = (t >= d) ? scnt[t - d] : 0;
            __syncthreads();
            scnt[t] += y;
            __syncthreads();
        }
        int excl = scnt[t] - v;
        int node = (b << BSH) + t;
        if (node < N) {
            cnt[node] = v;
            rowStart[node] = start + excl;
        }
        cur[t] = start + excl;
        __syncthreads();
        for (int p = t; p < len; p += FTH) {
            int pr = ec[p];
            int slot = atomicAdd(&cur[pr & BMASK], 1);
            sortedRow[slot] = pr >> BSH;
        }
    } else {
        // fallback: two global passes (round-3 path)
        for (int p = start + t; p < end; p += FTH) atomicAdd(&scnt[tmp[p] & BMASK], 1);
        __syncthreads();
        int v = scnt[t];
        for (int d = 1; d < 512; d <<= 1) {
            int y = (t >= d) ? scnt[t - d] : 0;
            __syncthreads();
            scnt[t] += y;
            __syncthreads();
        }
        int excl = scnt[t] - v;
        int node = (b << BSH) + t;
        if (node < N) {
            cnt[node] = v;
            rowStart[node] = start + excl;
        }
        cur[t] = start + excl;
        __syncthreads();
        for (int p = start + t; p < end; p += FTH) {
            int pr = tmp[p];
            int slot = atomicAdd(&cur[pr & BMASK], 1);
            sortedRow[slot] = pr >> BSH;
        }
    }
    if (b == NBUCK - 1 && t == 0) rowStart[N] = E;
}

// ---------- g = fp16( dinv * (x @ Wc^T) ) via MFMA 16x16x32 f16, 1 barrier/tile
__global__ __launch_bounds__(256) void k_gemm_mfma(const float* __restrict__ x,
                                                   const _Float16* __restrict__ Bfrag,
                                                   const int* __restrict__ cnt,
                                                   _Float16* __restrict__ g, int nrows) {
    __shared__ __align__(16) _Float16 xs[2][16 * AROW];
    int tid  = threadIdx.x;
    int lane = tid & 63;
    int w    = tid >> 6;      // wave 0..3
    int quad = lane >> 4;
    int lcol = lane & 15;

    const half8* Bv = (const half8*)Bfrag;
    half8 b0[8], b1[8];
#pragma unroll
    for (int kk = 0; kk < 8; ++kk) {
        b0[kk] = Bv[(w * 8 + kk) * 64 + lane];
        b1[kk] = Bv[((w + 4) * 8 + kk) * 64 + lane];
    }

    long base = (long)blockIdx.x * (16 * MT);
    for (int t = 0; t < MT; ++t) {
        long m0 = base + t * 16;
        _Float16* xb = xs[t & 1];
        // WAR-safe: barrier at tile t-1 guaranteed reads of this buffer done.
        const float4* xv = (const float4*)(x + m0 * KDIM);
#pragma unroll
        for (int ii = 0; ii < 4; ++ii) {
            int idx = tid + ii * 256;        // 16 rows x 64 float4
            int m = idx >> 6, k4 = idx & 63;
            float4 v = xv[idx];
            half4v hv = { (_Float16)v.x, (_Float16)v.y, (_Float16)v.z, (_Float16)v.w };
            *(half4v*)&xb[m * AROW + k4 * 4] = hv;
        }
        __syncthreads();

        float4v acc0 = {0.f, 0.f, 0.f, 0.f}, acc1 = {0.f, 0.f, 0.f, 0.f};
#pragma unroll
        for (int kk = 0; kk < 8; ++kk) {
            half8 a = *(const half8*)(&xb[lcol * AROW + kk * 32 + quad * 8]);
            acc0 = __builtin_amdgcn_mfma_f32_16x16x32_f16(a, b0[kk], acc0, 0, 0, 0);
            acc1 = __builtin_amdgcn_mfma_f32_16x16x32_f16(a, b1[kk], acc1, 0, 0, 0);
        }

        // C/D layout: col = lane&15, row = quad*4 + reg
#pragma unroll
        for (int r = 0; r < 4; ++r) {
            long node = m0 + quad * 4 + r;
            float di = rsqrtf((float)(cnt[node] + 1));   // deg = cnt + self-loop
            g[node * NDIM + w * 16 + lcol]        = (_Float16)(acc0[r] * di);
            g[node * NDIM + (w + 4) * 16 + lcol]  = (_Float16)(acc1[r] * di);
        }
    }
}

// ---------- gather + scale + bias + row L2-normalize (round-5, unchanged)
__global__ __launch_bounds__(256) void k_gather(const _Float16* __restrict__ g,
                                                const int* __restrict__ rowStart,
                                                const int* __restrict__ sortedRow,
                                                const int* __restrict__ cnt,
                                                const float* __restrict__ bg,
                                                float* __restrict__ out) {
    int lane = threadIdx.x & 63;
    int i = blockIdx.x * 4 + (threadIdx.x >> 6);   // node, N divisible by 4
    const int s = rowStart[i];
    const int e = rowStart[i + 1];
    const int g4  = lane >> 4;   // edge slot within wave: 0..3
    const int r16 = lane & 15;   // dim slot: halfs [r16*8, r16*8+8)

    const half8* __restrict__ gv = (const half8*)g;  // 16 half8 per row

    float acc[8];
#pragma unroll
    for (int j = 0; j < 8; ++j) acc[j] = 0.f;

#if HAS_FDOT2
    const half2v one2 = { (_Float16)1.0f, (_Float16)1.0f };
#endif

    int p = s;
    for (; p + 16 <= e; p += 16) {
        int r0 = sortedRow[p + g4];
        int r1 = sortedRow[p + 4 + g4];
        int r2 = sortedRow[p + 8 + g4];
        int r3 = sortedRow[p + 12 + g4];
        half8 v0 = gv[(size_t)r0 * 16 + r16];
        half8 v1 = gv[(size_t)r1 * 16 + r16];
        half8 v2 = gv[(size_t)r2 * 16 + r16];
        half8 v3 = gv[(size_t)r3 * 16 + r16];
#if HAS_FDOT2
#pragma unroll
        for (int j = 0; j < 8; ++j) {
            half2v a = { v0[j], v1[j] };
            half2v b = { v2[j], v3[j] };
            acc[j] = __builtin_amdgcn_fdot2(a, one2,
                     __builtin_amdgcn_fdot2(b, one2, acc[j], false), false);
        }
#else
#pragma unroll
        for (int j = 0; j < 8; ++j)
            acc[j] += ((float)v0[j] + (float)v1[j]) + ((float)v2[j] + (float)v3[j]);
#endif
    }
    if (p + 8 <= e) {
        int r0 = sortedRow[p + g4];
        int r1 = sortedRow[p + 4 + g4];
        half8 v0 = gv[(size_t)r0 * 16 + r16];
        half8 v1 = gv[(size_t)r1 * 16 + r16];
#if HAS_FDOT2
#pragma unroll
        for (int j = 0; j < 8; ++j) {
            half2v a = { v0[j], v1[j] };
            acc[j] = __builtin_amdgcn_fdot2(a, one2, acc[j], false);
        }
#else
#pragma unroll
        for (int j = 0; j < 8; ++j) acc[j] += (float)v0[j] + (float)v1[j];
#endif
        p += 8;
    }
    if (p + 4 <= e) {
        int r0 = sortedRow[p + g4];
        half8 v0 = gv[(size_t)r0 * 16 + r16];
#pragma unroll
        for (int j = 0; j < 8; ++j) acc[j] += (float)v0[j];
        p += 4;
    }
    if (p + g4 < e) {
        int r0 = sortedRow[p + g4];
        half8 v0 = gv[(size_t)r0 * 16 + r16];
#pragma unroll
        for (int j = 0; j < 8; ++j) acc[j] += (float)v0[j];
    }

#pragma unroll
    for (int j = 0; j < 8; ++j) {
        acc[j] += __shfl_xor(acc[j], 16);
        acc[j] += __shfl_xor(acc[j], 32);
    }

    half8 sv = gv[(size_t)i * 16 + r16];
#pragma unroll
    for (int j = 0; j < 8; ++j) acc[j] += (float)sv[j];

    float di = rsqrtf((float)(cnt[i] + 1));
    float4 b0 = ((const float4*)bg)[r16 * 2];
    float4 b1 = ((const float4*)bg)[r16 * 2 + 1];
    float v[8];
    v[0] = fmaf(di, acc[0], b0.x);
    v[1] = fmaf(di, acc[1], b0.y);
    v[2] = fmaf(di, acc[2], b0.z);
    v[3] = fmaf(di, acc[3], b0.w);
    v[4] = fmaf(di, acc[4], b1.x);
    v[5] = fmaf(di, acc[5], b1.y);
    v[6] = fmaf(di, acc[6], b1.z);
    v[7] = fmaf(di, acc[7], b1.w);

    float sq = 0.f;
#pragma unroll
    for (int j = 0; j < 8; ++j) sq += v[j] * v[j];
    sq += __shfl_xor(sq, 1);
    sq += __shfl_xor(sq, 2);
    sq += __shfl_xor(sq, 4);
    sq += __shfl_xor(sq, 8);
    float scale = 1.0f / fmaxf(sqrtf(sq), 1e-12f);

    if (g4 == 0) {
        float4 o0 = make_float4(v[0] * scale, v[1] * scale, v[2] * scale, v[3] * scale);
        float4 o1 = make_float4(v[4] * scale, v[5] * scale, v[6] * scale, v[7] * scale);
        ((float4*)out)[(size_t)i * 32 + r16 * 2]     = o0;
        ((float4*)out)[(size_t)i * 32 + r16 * 2 + 1] = o1;
    }
}

extern "C" void kernel_launch(void* const* d_in, const int* in_sizes, int n_in,
                              void* d_out, int out_size, void* d_ws, size_t ws_size,
                              hipStream_t stream) {
    const float* x  = (const float*)d_in[0];
    const int*   ei = (const int*)  d_in[1];
    const float* Wp = (const float*)d_in[2];
    const float* Wg = (const float*)d_in[3];
    const float* bg = (const float*)d_in[4];
    float* out = (float*)d_out;

    const int N = in_sizes[0] / KDIM;   // 100000
    const int E = in_sizes[1] / 2;      // 1600000

    const int NBLK  = (E + CHUNK - 1) / CHUNK;   // 500
    const int NBUCK = (N + BMASK) >> BSH;        // 196
    const int NE    = NBLK * NBUCK;              // 98000
    const int NSB   = (NE + 1023) >> 10;         // 96 scan chunks (<=128)

    // carve workspace (256B aligned)
    char* p = (char*)d_ws;
    auto carve = [&](size_t bytes) { void* r = (void*)p; p += (bytes + 255) & ~(size_t)255; return r; };
    _Float16* g      = (_Float16*)carve((size_t)N * NDIM * 2);  // 25.6 MB
    int*   sortedRow = (int*)  carve((size_t)E * 4);            // 6.4 MB
    int*   tmp       = (int*)  carve((size_t)E * 4);            // 6.4 MB (packed)
    _Float16* Bfrag  = (_Float16*)carve((size_t)KDIM * NDIM * 2);
    int*   cnt       = (int*)  carve((size_t)N * 4);
    int*   rowStart  = (int*)  carve((size_t)(N + 1) * 4);
    int*   hist      = (int*)  carve((size_t)NE * 4);
    int*   partials  = (int*)  carve((size_t)128 * 4);

    hipLaunchKernelGGL(k_prep, dim3(NBLK + 128), dim3(256), 0, stream,
                       Wp, Wg, Bfrag, ei, E, hist, NBLK, NBUCK, partials, NSB);
    hipLaunchKernelGGL(k_scan_lb, dim3(NSB), dim3(1024), 0, stream, hist, NE, partials);
    hipLaunchKernelGGL(k_phase3, dim3(NBLK), dim3(256), 0, stream, ei, E, hist, NBLK, NBUCK, tmp);
    hipLaunchKernelGGL(k_fine, dim3(NBUCK), dim3(FTH), 0, stream, tmp, hist, NBLK, NBUCK, N, E,
                       sortedRow, cnt, rowStart);
    hipLaunchKernelGGL(k_gemm_mfma, dim3(N / (16 * MT)), dim3(256), 0, stream, x, Bfrag, cnt, g, N);
    hipLaunchKernelGGL(k_gather, dim3(N / 4), dim3(256), 0, stream,
                       g, rowStart, sortedRow, cnt, bg, out);
}